// Round 4
// baseline (76.171 us; speedup 1.0000x reference)
//
#include <hip/hip_runtime.h>

#define FDIM   251
#define NFILT  80
#define KPAD   256        // K padded to 8 chunks of 32 (zeros past 250)
#define T_IN   64000
#define T_OUT  63750      // 64000 - 251 + 1
#define NCHUNK 1024       // output positions per block (4 waves x 16 strips x 16)
#define CPYLEN 648        // dwords per shifted copy; 648 % 32 == 8 -> bank stagger
#define XSTOT  (8 * CPYLEN)

typedef short bf16x8 __attribute__((ext_vector_type(8)));
typedef float f32x4  __attribute__((ext_vector_type(4)));

__device__ __forceinline__ unsigned short f2bf(float f) {
  unsigned int u = __float_as_uint(f);
  unsigned int r = (u + 0x7fffu + ((u >> 16) & 1u)) >> 16;   // RNE
  return (unsigned short)r;
}
__device__ __forceinline__ unsigned int packbf(float a, float b) {
  return (unsigned int)f2bf(a) | ((unsigned int)f2bf(b) << 16);
}

// ---------------------------------------------------------------------------
// Filter construction (validated rounds 1-2). Emits bf16 W[80][256].
// ---------------------------------------------------------------------------
__device__ __forceinline__ void norm_pm1_shared(float* a, float* scratch, int tid) {
  float v  = (tid < FDIM) ? a[tid] : 0.f;
  float mn = (tid < FDIM) ? v : 1e30f;
  float mx = (tid < FDIM) ? v : -1e30f;
  #pragma unroll
  for (int o = 32; o > 0; o >>= 1) {
    mn = fminf(mn, __shfl_down(mn, o));
    mx = fmaxf(mx, __shfl_down(mx, o));
  }
  const int wid = tid >> 6;
  if ((tid & 63) == 0) { scratch[wid] = mn; scratch[4 + wid] = mx; }
  __syncthreads();
  if (tid == 0) {
    scratch[0] = fminf(fminf(scratch[0], scratch[1]), fminf(scratch[2], scratch[3]));
    scratch[4] = fmaxf(fmaxf(scratch[4], scratch[5]), fmaxf(scratch[6], scratch[7]));
  }
  __syncthreads();
  const float gmn = scratch[0], gmx = scratch[4];
  const float nv = 2.f * (v - gmn) / (gmx - gmn + 1e-6f) - 1.f;
  __syncthreads();
  float s = (tid < FDIM) ? nv : 0.f;
  #pragma unroll
  for (int o = 32; o > 0; o >>= 1) s += __shfl_down(s, o);
  if ((tid & 63) == 0) scratch[wid] = s;
  __syncthreads();
  if (tid == 0) scratch[0] = (scratch[0] + scratch[1] + scratch[2] + scratch[3]) / 251.f;
  __syncthreads();
  const float mean = scratch[0];
  if (tid < FDIM) a[tid] = nv - mean;
  __syncthreads();
}

__global__ __launch_bounds__(256) void build_filters_kernel(
    const float* __restrict__ nf1, const float* __restrict__ nf2,
    const float* __restrict__ nf3, const float* __restrict__ nf4,
    const float* __restrict__ amp1, const float* __restrict__ amp2,
    unsigned short* __restrict__ Wbf) {
  __shared__ float ir1[FDIM], ir2[FDIM], casc[FDIM];
  __shared__ float scratch[8];
  const int f = blockIdx.x, tid = threadIdx.x;
  const float FS  = 16000.f;
  const float MF  = 50.f / 16000.f;
  const float PIF = 3.14159265358979323846f;
  const float TPI = 6.28318530717958647692f;

  const float f1 = fminf(fmaxf(fabsf(nf1[f]) + MF, 0.f), 0.5f);
  const float f2 = fminf(fmaxf(f1 + fabsf(nf2[f] - f1) + MF, 0.f), 0.5f);
  const float f3 = fminf(fmaxf(fabsf(nf3[f]) + MF, 0.f), 0.5f);
  const float f4 = fminf(fmaxf(f3 + fabsf(nf4[f] - f3) + MF, 0.f), 0.5f);
  const float a1 = fabsf(amp1[f]);
  const float a2 = fabsf(amp2[f]);

  if (tid < FDIM) {
    const float t = (float)(tid + 1) / FS;
    {
      const float fcs = 0.5f * (f1 + f2) * FS, bws = (f2 - f1) * FS;
      const float pb = PIF * bws;
      ir1[tid] = a1 * expf(-2.f * pb * pb * (t * t)) * cosf(TPI * fcs * t);
    }
    {
      const float fcs = 0.5f * (f3 + f4) * FS, bws = (f4 - f3) * FS;
      const float pb = PIF * bws;
      ir2[tid] = a2 * expf(-2.f * pb * pb * (t * t)) * cosf(TPI * fcs * t);
    }
  }
  __syncthreads();
  norm_pm1_shared(ir1, scratch, tid);
  norm_pm1_shared(ir2, scratch, tid);

  if (tid < FDIM) {
    const int i = tid;
    const int plo = (i - 125 > 0) ? (i - 125) : 0;
    const int phi = (i + 125 < 250) ? (i + 125) : 250;
    float s = 0.f;
    for (int p = plo; p <= phi; ++p) s += ir1[p] * ir2[p + 125 - i];
    casc[i] = s;
  }
  __syncthreads();
  norm_pm1_shared(casc, scratch, tid);

  if (tid < KPAD) {
    float v = 0.f;
    if (tid < FDIM) {
      const float win = 0.54f - 0.46f * cosf(TPI * ((float)tid / 250.f));
      v = casc[tid] * win;
    }
    Wbf[(size_t)f * KPAD + tid] = f2bf(v);
  }
}

// ---------------------------------------------------------------------------
// Implicit-GEMM conv via bf16 MFMA 16x16x32, operands swapped:
//   A = x sliding window (rows = time), B = W (cols = filter)
//   D[t'][f]: lane l -> col f = l&15, rows t' = 4*(l>>4) + r  (4 consecutive t)
// x staged in LDS as 8 element-shifted bf16-pair copies; lane's 8-consecutive
// A elements start at S = t_loc + m + 8h + 32c -> copy (m&7), dword index
// i0 = t_loc/2 + 4h + 4*(m>>3) + 16c  (16B aligned) => one ds_read_b128.
//   [round-3 bug: lane_q used 4*(m>>3); correct is (m>>3). That both read
//    wrong elements for m>=8 AND ran past the staged region -> NaN.]
// W fragments (B-operand) in registers: 5 Ftiles x 8 kchunks (160 VGPR).
// ---------------------------------------------------------------------------
__global__ __launch_bounds__(256, 2) void conv_mfma_kernel(
    const float* __restrict__ xin, const unsigned short* __restrict__ Wbf,
    float* __restrict__ outp) {
  __shared__ __align__(16) unsigned int xs[XSTOT];
  const int tid = threadIdx.x;
  const int n0  = blockIdx.x * NCHUNK;
  const int b   = blockIdx.y;
  const int l   = tid & 63, w = tid >> 6;
  const int m   = l & 15, h = l >> 4;

  // ---- W fragments (B-operand): lane -> col f = m, k = 8*h + j + 32*c ----
  const short* Wp = (const short*)Wbf;
  bf16x8 wfr[5][8];
  #pragma unroll
  for (int mt = 0; mt < 5; ++mt)
    #pragma unroll
    for (int c = 0; c < 8; ++c)
      wfr[mt][c] = *(const bf16x8*)(Wp + (mt * 16 + m) * KPAD + c * 32 + h * 8);

  // ---- stage x as 8 shifted bf16-pair copies: C_j[i] = (x[2i+j], x[2i+j+1]) ----
  const float* xg = xin + (size_t)b * T_IN;
  for (int i = tid; i < CPYLEN - 4; i += 256) {
    float e[10];
    #pragma unroll
    for (int q = 0; q < 10; ++q) {
      const int g = n0 + 2 * i + q;
      e[q] = (g < T_IN) ? xg[g] : 0.f;
    }
    #pragma unroll
    for (int j = 0; j < 8; ++j)
      xs[j * CPYLEN + i] = packbf(e[j], e[j + 1]);
  }
  __syncthreads();

  // lane-constant A addressing (quad-dword units): i0/4 = t_loc/8 + h + (m>>3) + 4c
  const unsigned int* psrc = xs + (m & 7) * CPYLEN;
  const int lane_q = h + (m >> 3);              // FIXED (was h + (m>>3)*4)

  for (int i = 0; i < 16; ++i) {
    const int t_loc = i * 64 + w * 16;
    const int q0 = (t_loc >> 3) + lane_q;

    f32x4 acc[5];
    #pragma unroll
    for (int mt = 0; mt < 5; ++mt) acc[mt] = (f32x4){0.f, 0.f, 0.f, 0.f};

    #pragma unroll
    for (int c = 0; c < 8; ++c) {
      const bf16x8 xf = *(const bf16x8*)(psrc + 4 * (q0 + 4 * c));
      #pragma unroll
      for (int mt = 0; mt < 5; ++mt)
        acc[mt] = __builtin_amdgcn_mfma_f32_16x16x32_bf16(xf, wfr[mt][c], acc[mt], 0, 0, 0);
    }

    const int tg = n0 + t_loc + 4 * h;          // D rows = 4h + r -> consecutive t
    #pragma unroll
    for (int mt = 0; mt < 5; ++mt) {
      const int f = mt * 16 + m;                // D col = l&15
      const size_t row = ((size_t)b * NFILT + f) * T_OUT;
      if (tg < T_OUT)
        *(float2*)&outp[row + tg] = make_float2(acc[mt][0], acc[mt][1]);
      if (tg + 2 < T_OUT)
        *(float2*)&outp[row + tg + 2] = make_float2(acc[mt][2], acc[mt][3]);
    }
  }
}

// ---------------------------------------------------------------------------
extern "C" void kernel_launch(void* const* d_in, const int* in_sizes, int n_in,
                              void* d_out, int out_size, void* d_ws, size_t ws_size,
                              hipStream_t stream) {
  const float* x    = (const float*)d_in[0];
  const float* nf1  = (const float*)d_in[1];
  const float* nf2  = (const float*)d_in[2];
  const float* nf3  = (const float*)d_in[3];
  const float* nf4  = (const float*)d_in[4];
  const float* amp1 = (const float*)d_in[5];
  const float* amp2 = (const float*)d_in[6];
  unsigned short* Wbf = (unsigned short*)d_ws;   // 80*256*2 = 40 KB scratch
  float* out = (float*)d_out;

  build_filters_kernel<<<NFILT, 256, 0, stream>>>(nf1, nf2, nf3, nf4, amp1, amp2, Wbf);

  dim3 grid((T_OUT + NCHUNK - 1) / NCHUNK, 8, 1);   // 63 x 8
  conv_mfma_kernel<<<grid, 256, 0, stream>>>(x, Wbf, out);
}

// Round 5
// 63.327 us; speedup vs baseline: 1.2028x; 1.2028x over previous
//
#include <hip/hip_runtime.h>

#define FDIM   251
#define NFILT  80
#define KPAD   256        // K padded to 8 chunks of 32 (zeros past 250)
#define T_IN   64000
#define T_OUT  63750      // 64000 - 251 + 1
#define NCHUNK 1024       // output positions per block (16 strips x 64 t)
#define CPYLEN 648        // dwords per shifted copy; 648 % 32 == 8 -> bank stagger
#define XSTOT  (8 * CPYLEN)
#define TROW   68         // transpose tile row stride (dwords), [80][68]
#define TBSTR  (NFILT * TROW)

typedef short bf16x8 __attribute__((ext_vector_type(8)));
typedef float f32x4  __attribute__((ext_vector_type(4)));

__device__ __forceinline__ unsigned short f2bf(float f) {
  unsigned int u = __float_as_uint(f);
  unsigned int r = (u + 0x7fffu + ((u >> 16) & 1u)) >> 16;   // RNE
  return (unsigned short)r;
}
__device__ __forceinline__ unsigned int packbf(float a, float b) {
  return (unsigned int)f2bf(a) | ((unsigned int)f2bf(b) << 16);
}

// ---------------------------------------------------------------------------
// Filter construction (validated rounds 1-4). Emits bf16 W[80][256].
// ---------------------------------------------------------------------------
__device__ __forceinline__ void norm_pm1_shared(float* a, float* scratch, int tid) {
  float v  = (tid < FDIM) ? a[tid] : 0.f;
  float mn = (tid < FDIM) ? v : 1e30f;
  float mx = (tid < FDIM) ? v : -1e30f;
  #pragma unroll
  for (int o = 32; o > 0; o >>= 1) {
    mn = fminf(mn, __shfl_down(mn, o));
    mx = fmaxf(mx, __shfl_down(mx, o));
  }
  const int wid = tid >> 6;
  if ((tid & 63) == 0) { scratch[wid] = mn; scratch[4 + wid] = mx; }
  __syncthreads();
  if (tid == 0) {
    scratch[0] = fminf(fminf(scratch[0], scratch[1]), fminf(scratch[2], scratch[3]));
    scratch[4] = fmaxf(fmaxf(scratch[4], scratch[5]), fmaxf(scratch[6], scratch[7]));
  }
  __syncthreads();
  const float gmn = scratch[0], gmx = scratch[4];
  const float nv = 2.f * (v - gmn) / (gmx - gmn + 1e-6f) - 1.f;
  __syncthreads();
  float s = (tid < FDIM) ? nv : 0.f;
  #pragma unroll
  for (int o = 32; o > 0; o >>= 1) s += __shfl_down(s, o);
  if ((tid & 63) == 0) scratch[wid] = s;
  __syncthreads();
  if (tid == 0) scratch[0] = (scratch[0] + scratch[1] + scratch[2] + scratch[3]) / 251.f;
  __syncthreads();
  const float mean = scratch[0];
  if (tid < FDIM) a[tid] = nv - mean;
  __syncthreads();
}

__global__ __launch_bounds__(256) void build_filters_kernel(
    const float* __restrict__ nf1, const float* __restrict__ nf2,
    const float* __restrict__ nf3, const float* __restrict__ nf4,
    const float* __restrict__ amp1, const float* __restrict__ amp2,
    unsigned short* __restrict__ Wbf) {
  __shared__ float ir1[FDIM], ir2[FDIM], casc[FDIM];
  __shared__ float scratch[8];
  const int f = blockIdx.x, tid = threadIdx.x;
  const float FS  = 16000.f;
  const float MF  = 50.f / 16000.f;
  const float PIF = 3.14159265358979323846f;
  const float TPI = 6.28318530717958647692f;

  const float f1 = fminf(fmaxf(fabsf(nf1[f]) + MF, 0.f), 0.5f);
  const float f2 = fminf(fmaxf(f1 + fabsf(nf2[f] - f1) + MF, 0.f), 0.5f);
  const float f3 = fminf(fmaxf(fabsf(nf3[f]) + MF, 0.f), 0.5f);
  const float f4 = fminf(fmaxf(f3 + fabsf(nf4[f] - f3) + MF, 0.f), 0.5f);
  const float a1 = fabsf(amp1[f]);
  const float a2 = fabsf(amp2[f]);

  if (tid < FDIM) {
    const float t = (float)(tid + 1) / FS;
    {
      const float fcs = 0.5f * (f1 + f2) * FS, bws = (f2 - f1) * FS;
      const float pb = PIF * bws;
      ir1[tid] = a1 * expf(-2.f * pb * pb * (t * t)) * cosf(TPI * fcs * t);
    }
    {
      const float fcs = 0.5f * (f3 + f4) * FS, bws = (f4 - f3) * FS;
      const float pb = PIF * bws;
      ir2[tid] = a2 * expf(-2.f * pb * pb * (t * t)) * cosf(TPI * fcs * t);
    }
  }
  __syncthreads();
  norm_pm1_shared(ir1, scratch, tid);
  norm_pm1_shared(ir2, scratch, tid);

  if (tid < FDIM) {
    const int i = tid;
    const int plo = (i - 125 > 0) ? (i - 125) : 0;
    const int phi = (i + 125 < 250) ? (i + 125) : 250;
    float s = 0.f;
    for (int p = plo; p <= phi; ++p) s += ir1[p] * ir2[p + 125 - i];
    casc[i] = s;
  }
  __syncthreads();
  norm_pm1_shared(casc, scratch, tid);

  if (tid < KPAD) {
    float v = 0.f;
    if (tid < FDIM) {
      const float win = 0.54f - 0.46f * cosf(TPI * ((float)tid / 250.f));
      v = casc[tid] * win;
    }
    Wbf[(size_t)f * KPAD + tid] = f2bf(v);
  }
}

// ---------------------------------------------------------------------------
// Implicit-GEMM conv, r2 orientation (A=W, B=x -> D[f-row][t-col]), with an
// LDS-transpose epilogue producing contiguous 256B-per-instr output stores.
// Per strip (64 t): 4 waves deposit D into time-major tile tb[f][t_loc]
// (b32 writes, 2-way banks = free), lgkm-only barrier, then each wave stores
// 20 f-rows as 2-rows-per-instr float2 runs (256B contiguous per row-half).
// ---------------------------------------------------------------------------
__global__ __launch_bounds__(256, 2) void conv_mfma_kernel(
    const float* __restrict__ xin, const unsigned short* __restrict__ Wbf,
    float* __restrict__ outp) {
  __shared__ __align__(16) unsigned int xs[XSTOT];
  __shared__ __align__(16) float tbuf[2 * TBSTR];     // double-buffered transpose
  const int tid = threadIdx.x;
  const int n0  = blockIdx.x * NCHUNK;
  const int b   = blockIdx.y;
  const int l   = tid & 63, w = tid >> 6;
  const int m   = l & 15, h = l >> 4;

  // ---- W fragments (A-operand): lane row = m -> W[mt*16+m][k=8h+j+32c] ----
  const short* Wp = (const short*)Wbf;
  bf16x8 afr[5][8];
  #pragma unroll
  for (int mt = 0; mt < 5; ++mt)
    #pragma unroll
    for (int c = 0; c < 8; ++c)
      afr[mt][c] = *(const bf16x8*)(Wp + (mt * 16 + m) * KPAD + c * 32 + h * 8);

  // ---- stage x as 8 shifted bf16-pair copies: C_j[i] = (x[2i+j], x[2i+j+1]) ----
  const float* xg = xin + (size_t)b * T_IN;
  for (int i = tid; i < CPYLEN - 4; i += 256) {
    float e[10];
    #pragma unroll
    for (int q = 0; q < 10; ++q) {
      const int g = n0 + 2 * i + q;
      e[q] = (g < T_IN) ? xg[g] : 0.f;
    }
    #pragma unroll
    for (int j = 0; j < 8; ++j)
      xs[j * CPYLEN + i] = packbf(e[j], e[j + 1]);
  }
  __syncthreads();

  // lane-constant B(x) addressing: start S = t_loc + m + 8h + 32c
  // copy j = m&7, quad-dword index = t_loc/8 + h + (m>>3) + 4c  (validated r4)
  const unsigned int* psrc = xs + (m & 7) * CPYLEN;
  const int lane_q = h + (m >> 3);

  for (int i = 0; i < 16; ++i) {
    const int t_loc = i * 64 + w * 16;
    const int q0 = (t_loc >> 3) + lane_q;

    f32x4 acc[5];
    #pragma unroll
    for (int mt = 0; mt < 5; ++mt) acc[mt] = (f32x4){0.f, 0.f, 0.f, 0.f};

    #pragma unroll
    for (int c = 0; c < 8; ++c) {
      const bf16x8 xf = *(const bf16x8*)(psrc + 4 * (q0 + 4 * c));
      #pragma unroll
      for (int mt = 0; mt < 5; ++mt)
        acc[mt] = __builtin_amdgcn_mfma_f32_16x16x32_bf16(afr[mt][c], xf, acc[mt], 0, 0, 0);
    }

    // ---- deposit D tile time-major: tb[f][t_local] ----
    // lane (m,h) holds D[f = mt*16+4h+r][t_local = w*16+m]
    float* tb = tbuf + (i & 1) * TBSTR;
    #pragma unroll
    for (int mt = 0; mt < 5; ++mt)
      #pragma unroll
      for (int r = 0; r < 4; ++r)
        tb[(mt * 16 + 4 * h + r) * TROW + w * 16 + m] = acc[mt][r];

    // lgkm-only barrier: orders LDS writes across waves WITHOUT the vmcnt(0)
    // drain __syncthreads would add (keeps the global-store queue in flight).
    asm volatile("s_waitcnt lgkmcnt(0)\n\ts_barrier" ::: "memory");

    // ---- coalesced store: per instr 2 f-rows x 32 lanes x float2 = 2x256B ----
    const int t_base = n0 + i * 64;
    const int t2 = 2 * (l & 31);
    const int tg = t_base + t2;            // even; T_OUT even -> pair never straddles
    #pragma unroll
    for (int jj = 0; jj < 10; ++jj) {
      const int fr = 20 * w + 2 * jj + (l >> 5);
      const float2 v = *(const float2*)&tb[fr * TROW + t2];
      if (tg < T_OUT)
        *(float2*)&outp[((size_t)b * NFILT + fr) * T_OUT + tg] = v;
    }
    // double buffer: next strip writes the other tile; single barrier is safe
    // (a wave can only write buf[i+1 mod 2] after ALL waves passed barrier i).
  }
}

// ---------------------------------------------------------------------------
extern "C" void kernel_launch(void* const* d_in, const int* in_sizes, int n_in,
                              void* d_out, int out_size, void* d_ws, size_t ws_size,
                              hipStream_t stream) {
  const float* x    = (const float*)d_in[0];
  const float* nf1  = (const float*)d_in[1];
  const float* nf2  = (const float*)d_in[2];
  const float* nf3  = (const float*)d_in[3];
  const float* nf4  = (const float*)d_in[4];
  const float* amp1 = (const float*)d_in[5];
  const float* amp2 = (const float*)d_in[6];
  unsigned short* Wbf = (unsigned short*)d_ws;   // 80*256*2 = 40 KB scratch
  float* out = (float*)d_out;

  build_filters_kernel<<<NFILT, 256, 0, stream>>>(nf1, nf2, nf3, nf4, amp1, amp2, Wbf);

  dim3 grid((T_OUT + NCHUNK - 1) / NCHUNK, 8, 1);   // 63 x 8
  conv_mfma_kernel<<<grid, 256, 0, stream>>>(x, Wbf, out);
}